// Round 16
// baseline (2691.233 us; speedup 1.0000x reference)
//
#include <hip/hip_runtime.h>

#define B_ 8
#define H_ 8
#define DM 512
#define DH 64
#define LMAX 2048
#define COUT 2

typedef __attribute__((ext_vector_type(8))) short frag8;
typedef __attribute__((ext_vector_type(4))) float f32x4;

// XOR-swizzled LDS offset (shorts): row stride 32, sub-block perm kills
// power-of-2 bank aliasing with zero padding. Banks: exactly 2-way (free).
__device__ __forceinline__ int swz(int row, int sub) {
  return row * 32 + ((sub ^ ((row >> 1) & 3)) * 8);
}

__device__ __forceinline__ short f2bf(float v) {
  unsigned u = __float_as_uint(v);
  unsigned r = (u + 0x7fffu + ((u >> 16) & 1u)) >> 16;   // RNE
  return (short)r;
}
__device__ __forceinline__ float bf2f(short s) {
  return __uint_as_float(((unsigned)(unsigned short)s) << 16);
}

// ---------------- JAX threefry2x32 ----------------
__device__ __forceinline__ void tf2x32(unsigned k0, unsigned k1, unsigned x0, unsigned x1,
                                       unsigned& o0, unsigned& o1) {
  unsigned ks2 = k0 ^ k1 ^ 0x1BD11BDAu;
  x0 += k0; x1 += k1;
#define RND(r) { x0 += x1; x1 = (x1 << r) | (x1 >> (32 - r)); x1 ^= x0; }
  RND(13) RND(15) RND(26) RND(6)  x0 += k1;  x1 += ks2 + 1u;
  RND(17) RND(29) RND(16) RND(24) x0 += ks2; x1 += k0 + 2u;
  RND(13) RND(15) RND(26) RND(6)  x0 += k0;  x1 += k1 + 3u;
  RND(17) RND(29) RND(16) RND(24) x0 += k1;  x1 += ks2 + 4u;
  RND(13) RND(15) RND(26) RND(6)  x0 += ks2; x1 += k0 + 5u;
#undef RND
  o0 = x0; o1 = x1;
}

// VERIFIED (R7, absmax 0.0): Variant B partitionable. DO NOT TOUCH.
__global__ void idx_kernel(int* __restrict__ idxArr, int L, int U, int layer) {
  int p = blockIdx.x * 256 + threadIdx.x;
  int half = L * U;
  if (p >= half) return;
  unsigned fk0, fk1, k20, k21, o0, o1;
  tf2x32(0u, 42u, 0u, (unsigned)layer, fk0, fk1);
  tf2x32(fk0, fk1, 0u, 1u, k20, k21);
  tf2x32(k20, k21, 0u, (unsigned)p, o0, o1);
  idxArr[p] = (int)((o0 ^ o1) & (unsigned)(L - 1));
}

// ---------------- token embed + positional encoding ----------------
__global__ void embed_kernel(const float* __restrict__ xe, const float* __restrict__ tw,
                             float* __restrict__ X) {
  int i = blockIdx.x * 256 + threadIdx.x;
  int c = i % DM;
  int l = (i / DM) % LMAX;
  int b = i / (DM * LMAX);
  int lm = (l + LMAX - 1) & (LMAX - 1);
  int lp = (l + 1) & (LMAX - 1);
  const float* xb = xe + b * LMAX;
  float tok = tw[c * 3 + 0] * xb[lm] + tw[c * 3 + 1] * xb[l] + tw[c * 3 + 2] * xb[lp];
  float freq = expf(-(float)(c & ~1) * (9.210340371976184f / 512.0f));
  float ang = (float)l * freq;
  float pe = (c & 1) ? cosf(ang) : sinf(ang);
  X[i] = tok + pe;
}

// ---------------- weight split: f32 -> 3 bf16 planes ----------------
__global__ void wsplit_kernel(const float* __restrict__ W, short* __restrict__ P0,
                              short* __restrict__ P1, short* __restrict__ P2, int n) {
  int i = blockIdx.x * 256 + threadIdx.x;
  if (i >= n) return;
  float v = W[i];
  short h0 = f2bf(v);
  float r1 = v - bf2f(h0);
  short h1 = f2bf(r1);
  float r2 = r1 - bf2f(h1);
  P0[i] = h0; P1[i] = h1; P2[i] = f2bf(r2);
}

// conv weight transpose + split: Pt[n][tap*512+k] = split(w[n][k][tap])
__global__ void wt3_kernel(const float* __restrict__ w, short* __restrict__ P0,
                           short* __restrict__ P1, short* __restrict__ P2) {
  int i = blockIdx.x * 256 + threadIdx.x;   // 512*1536
  int n = i / 1536, r = i - n * 1536, tap = r >> 9, k = r & 511;
  float v = w[((size_t)n * DM + k) * 3 + tap];
  short h0 = f2bf(v);
  float r1 = v - bf2f(h0);
  short h1 = f2bf(r1);
  float r2 = r1 - bf2f(h1);
  P0[i] = h0; P1[i] = h1; P2[i] = f2bf(r2);
}

// ---------------- bf16x3-split MFMA GEMM, 6-product ----------------
// BM=BN=128, BK=32, 4 waves (2x2 of 64x64). XCD-aware swizzle; XOR-swizzled
// LDS (49KB -> 3 blocks/CU). 6 of 9 split products (dropped terms ~2^-26 rel,
// below f32 per-product rounding).
template <int ACT, int QKV, int ACC, int CONV>
__global__ __launch_bounds__(256, 3) void mgemm(const float* __restrict__ A,
                                                const short* __restrict__ W0g,
                                                const short* __restrict__ W1g,
                                                const short* __restrict__ W2g,
                                                const float* __restrict__ bias,
                                                float* __restrict__ C, int L, int Ktot) {
  __shared__ short A0[128 * 32], A1[128 * 32], A2[128 * 32];
  __shared__ short B0[128 * 32], B1[128 * 32], B2[128 * 32];
  int tid = threadIdx.x;
  int lane = tid & 63, wave = tid >> 6;
  // XCD-aware swizzle: each XCD gets one m-row phase, iterating n fastest.
  int gx = gridDim.x;
  int flat = blockIdx.y * gx + blockIdx.x;
  int mB, nB;
  if ((gridDim.y & 7) == 0) {
    int phase = flat & 7, sup = flat >> 3;
    nB = sup % gx;
    mB = phase + 8 * (sup / gx);
  } else {
    nB = blockIdx.x; mB = blockIdx.y;
  }
  int n0 = nB * 128, m0 = mB * 128;
  int wm = (wave >> 1) * 64, wn = (wave & 1) * 64;
  f32x4 acc[4][4] = {};
  int lrow = lane & 15, lq = lane >> 4;

  for (int k0 = 0; k0 < Ktot; k0 += 32) {
    int tap = 0, kcol = k0;
    if (CONV) { tap = k0 >> 9; kcol = k0 & 511; }
    // ---- stage A: one row x one 8-k group per thread -> 3 frag8 ----
#pragma unroll
    for (int it = 0; it < 2; ++it) {
      int f = tid + it * 256;            // 0..511 (row, kgroup) slots
      int r = f >> 2, kq = f & 3;
      const float* ap;
      if (CONV) {
        int row = m0 + r;
        int b = row / L, l = row - b * L;
        int le = l + tap - 1;
        le = (le < 0) ? le + L : (le >= L ? le - L : le);
        ap = A + ((size_t)(b * L + le) * DM + kcol + kq * 8);
      } else {
        ap = A + ((size_t)(m0 + r) * DM + k0 + kq * 8);
      }
      float4 va = *(const float4*)ap;
      float4 vb = *(const float4*)(ap + 4);
      float v[8] = {va.x, va.y, va.z, va.w, vb.x, vb.y, vb.z, vb.w};
      frag8 h0, h1, h2;
#pragma unroll
      for (int c = 0; c < 8; ++c) {
        short t0 = f2bf(v[c]);
        float r1 = v[c] - bf2f(t0);
        short t1 = f2bf(r1);
        float r2 = r1 - bf2f(t1);
        h0[c] = t0; h1[c] = t1; h2[c] = f2bf(r2);
      }
      int off = swz(r, kq);
      *(frag8*)&A0[off] = h0;
      *(frag8*)&A1[off] = h1;
      *(frag8*)&A2[off] = h2;
    }
    // ---- stage B (copy pre-split planes, 16B coalesced) ----
#pragma unroll
    for (int it = 0; it < 2; ++it) {
      int f = tid + it * 256;            // 0..511 frag8 slots
      int r = f >> 2, kq = f & 3;
      size_t goff = (size_t)(n0 + r) * Ktot + k0 + kq * 8;
      int off = swz(r, kq);
      *(frag8*)&B0[off] = *(const frag8*)&W0g[goff];
      *(frag8*)&B1[off] = *(const frag8*)&W1g[goff];
      *(frag8*)&B2[off] = *(const frag8*)&W2g[goff];
    }
    __syncthreads();
    frag8 a0f[4], a1f[4], a2f[4];
#pragma unroll
    for (int ti = 0; ti < 4; ++ti) {
      int off = swz(wm + ti * 16 + lrow, lq);
      a0f[ti] = *(const frag8*)&A0[off];
      a1f[ti] = *(const frag8*)&A1[off];
      a2f[ti] = *(const frag8*)&A2[off];
    }
#pragma unroll
    for (int tj = 0; tj < 4; ++tj) {
      int off = swz(wn + tj * 16 + lrow, lq);
      frag8 b0 = *(const frag8*)&B0[off];
      frag8 b1 = *(const frag8*)&B1[off];
      frag8 b2 = *(const frag8*)&B2[off];
#pragma unroll
      for (int ti = 0; ti < 4; ++ti) {
        f32x4 ac = acc[ti][tj];
        ac = __builtin_amdgcn_mfma_f32_16x16x32_bf16(a1f[ti], b1, ac, 0, 0, 0);
        ac = __builtin_amdgcn_mfma_f32_16x16x32_bf16(a0f[ti], b2, ac, 0, 0, 0);
        ac = __builtin_amdgcn_mfma_f32_16x16x32_bf16(a2f[ti], b0, ac, 0, 0, 0);
        ac = __builtin_amdgcn_mfma_f32_16x16x32_bf16(a0f[ti], b1, ac, 0, 0, 0);
        ac = __builtin_amdgcn_mfma_f32_16x16x32_bf16(a1f[ti], b0, ac, 0, 0, 0);
        ac = __builtin_amdgcn_mfma_f32_16x16x32_bf16(a0f[ti], b0, ac, 0, 0, 0);
        acc[ti][tj] = ac;
      }
    }
    __syncthreads();
  }
  // epilogue: C/D map col=lane&15, row=(lane>>4)*4+reg
#pragma unroll
  for (int ti = 0; ti < 4; ++ti) {
#pragma unroll
    for (int tj = 0; tj < 4; ++tj) {
#pragma unroll
      for (int r = 0; r < 4; ++r) {
        int row = m0 + wm + ti * 16 + lq * 4 + r;
        int col = n0 + wn + tj * 16 + lrow;
        float v = acc[ti][tj][r];
        if (!CONV) v += bias[col];
        if (ACT) v = 0.5f * v * (1.0f + erff(v * 0.70710678118654752f));
        if (QKV) {
          int b = row / L, l = row - b * L;
          int h = col >> 6, d = col & 63;
          C[(((size_t)b * H_ + h) * L + l) * DH + d] = v;
        } else if (ACC) {
          C[(size_t)row * DM + col] += v;
        } else {
          C[(size_t)row * DM + col] = v;
        }
      }
    }
  }
}

// ---------------- conv epilogue: BN + ELU ----------------
__global__ void bnelu_kernel(float* __restrict__ Y, const float* __restrict__ cb,
                             const float* __restrict__ g, const float* __restrict__ be) {
  int i = blockIdx.x * 256 + threadIdx.x;
  int c = i % DM;
  const float invs = 0.9999950000374997f;  // 1/sqrt(1+1e-5)
  float z = Y[i] + cb[c];
  z = z * invs * g[c] + be[c];
  Y[i] = z > 0.f ? z : expm1f(z);
}

// ---------------- qkM: lane=(dchunk,sample), 3 shuffles per 8-sample pass ----------------
template <int U>
__global__ void qkM_t(const float* __restrict__ Q, const float* __restrict__ Kd,
                      const int* __restrict__ idxArr, float* __restrict__ Mout, int L) {
  int lane = threadIdx.x & 63, wv = threadIdx.x >> 6;
  int row = blockIdx.x * 4 + wv;
  int l = row % L, bh = row / L;
  int u = lane & 7, dc = lane >> 3;       // sample slot, d-chunk
  const float* Qb = Q + ((size_t)bh * L + l) * DH + dc * 8;
  float4 q0 = *(const float4*)(Qb);
  float4 q1 = *(const float4*)(Qb + 4);
  const float* Kb = Kd + (size_t)bh * L * DH;
  const int* ip = idxArr + l * U;
  const int NP = (U + 7) / 8;
  float mx = -1e30f, sm = 0.f;
#pragma unroll
  for (int p = 0; p < NP; ++p) {
    int s = p * 8 + u;
    bool valid = (s < U);
    int ki = ip[valid ? s : 0];
    const float* kr = Kb + (size_t)ki * DH + dc * 8;
    float4 k0 = *(const float4*)(kr);
    float4 k1 = *(const float4*)(kr + 4);
    float d = q0.x * k0.x + q0.y * k0.y + q0.z * k0.z + q0.w * k0.w +
              q1.x * k1.x + q1.y * k1.y + q1.z * k1.z + q1.w * k1.w;
    d += __shfl_xor(d, 8, 64);
    d += __shfl_xor(d, 16, 64);
    d += __shfl_xor(d, 32, 64);
    if (valid) { mx = fmaxf(mx, d); sm += d; }
  }
#pragma unroll
  for (int o = 1; o <= 4; o <<= 1) {
    mx = fmaxf(mx, __shfl_xor(mx, o, 64));
    sm += __shfl_xor(sm, o, 64);
  }
  if (lane == 0) Mout[row] = mx - sm / (float)U;
}

// ---------------- top-U per bh ----------------
__global__ void topk_kernel(const float* __restrict__ M, int* __restrict__ top, int L, int U) {
  __shared__ float vals[LMAX];
  __shared__ float rv[256];
  __shared__ int ri[256];
  int bh = blockIdx.x, tid = threadIdx.x;
  for (int j = tid; j < L; j += 256) vals[j] = M[(size_t)bh * L + j];
  __syncthreads();
  for (int u = 0; u < U; ++u) {
    float bv = -1e30f; int bi = L;
    for (int j = tid; j < L; j += 256) {
      float v = vals[j];
      if (v > bv) { bv = v; bi = j; }
    }
    rv[tid] = bv; ri[tid] = bi;
    __syncthreads();
    for (int s = 128; s >= 1; s >>= 1) {
      if (tid < s) {
        float ov = rv[tid + s]; int oi = ri[tid + s];
        if (ov > rv[tid] || (ov == rv[tid] && oi < ri[tid])) { rv[tid] = ov; ri[tid] = oi; }
      }
      __syncthreads();
    }
    if (tid == 0) { top[bh * U + u] = ri[0]; vals[ri[0]] = -1e30f; }
    __syncthreads();
  }
}

// ---------------- v mean over L per (bh,d) ----------------
__global__ void vmean_kernel(const float* __restrict__ V, float* __restrict__ VM, int L) {
  __shared__ float red[256];
  int bh = blockIdx.x, tid = threadIdx.x, d = tid & 63, sq = tid >> 6;
  float s = 0.f;
  for (int l = sq; l < L; l += 4) s += V[((size_t)bh * L + l) * DH + d];
  red[tid] = s;
  __syncthreads();
  if (sq == 0) VM[bh * DH + d] = (red[d] + red[d + 64] + red[d + 128] + red[d + 192]) / (float)L;
}

// ---------------- fill ctx (g,L,DM) with v-mean ----------------
__global__ void fill_kernel(const float* __restrict__ VM, float* __restrict__ O, int L) {
  size_t i = (size_t)blockIdx.x * 256 + threadIdx.x;
  int c = (int)(i % DM);
  int b = (int)(i / ((size_t)L * DM));
  O[i] = VM[b * DM + c];
}

// ---------------- flash-style attention for selected queries ----------------
__global__ __launch_bounds__(256) void attn_fused(const float* __restrict__ Q,
                                                  const float* __restrict__ Kd,
                                                  const float* __restrict__ V,
                                                  const int* __restrict__ top,
                                                  float* __restrict__ O, int L, int U) {
  __shared__ float Qs[8][64];
  __shared__ float Kt[64][65];
  __shared__ float Vs[64][68];
  __shared__ float ps[8][64];
  __shared__ int lst[8];
  int nch = (U + 7) >> 3;
  int bh = blockIdx.x / nch, ch = blockIdx.x - bh * nch;
  int u0g = ch * 8;
  int qn = U - u0g; if (qn > 8) qn = 8;
  int tid = threadIdx.x, lane = tid & 63, wv = tid >> 6;
  if (tid < qn) lst[tid] = top[bh * U + u0g + tid];
  __syncthreads();
  for (int idx = tid; idx < qn * 64; idx += 256) {
    int u = idx >> 6, d = idx & 63;
    Qs[u][d] = Q[((size_t)bh * L + lst[u]) * DH + d];
  }
  __syncthreads();
  int ua = wv, ub = wv + 4;
  bool hasA = ua < qn, hasB = ub < qn;
  float m0 = -1e30f, l0 = 0.f, o0 = 0.f;
  float m1 = -1e30f, l1 = 0.f, o1 = 0.f;
  const float* Kbase = Kd + (size_t)bh * L * DH;
  const float* Vbase = V + (size_t)bh * L * DH;
  for (int t0 = 0; t0 < L; t0 += 64) {
#pragma unroll
    for (int it = 0; it < 4; ++it) {
      int idx = tid + it * 256;
      int j = idx >> 4, d4 = (idx & 15) * 4;
      float4 kv = *(const float4*)(Kbase + (size_t)(t0 + j) * DH + d4);
      Kt[d4 + 0][j] = kv.x; Kt[d4 + 1][j] = kv.y;
      Kt[d4 + 2][j] = kv.z; Kt[d4 + 3][j] = kv.w;
      *(float4*)&Vs[j][d4] = *(const float4*)(Vbase + (size_t)(t0 + j) * DH + d4);
    }
    __syncthreads();
    float s0 = 0.f, s1 = 0.f;
#pragma unroll 16
    for (int d = 0; d < 64; ++d) {
      float kd = Kt[d][lane];
      s0 += kd * Qs[ua & 7][d];
      s1 += kd * Qs[ub & 7][d];
    }
    s0 *= 0.125f; s1 *= 0.125f;
    if (hasA) {
      float tm = s0;
#pragma unroll
      for (int o = 32; o >= 1; o >>= 1) tm = fmaxf(tm, __shfl_xor(tm, o, 64));
      float nm = fmaxf(m0, tm);
      float alpha = expf(m0 - nm);
      float p = expf(s0 - nm);
      float tsum = p;
#pragma unroll
      for (int o = 32; o >= 1; o >>= 1) tsum += __shfl_xor(tsum, o, 64);
      l0 = l0 * alpha + tsum;
      m0 = nm;
      ps[ua][lane] = p;
      o0 *= alpha;
    }
    if (hasB) {
      float tm = s1;
#pragma unroll
      for (int o = 32; o >= 1; o >>= 1) tm = fmaxf(tm, __shfl_xor(tm, o, 64));
      float nm = fmaxf(m1, tm);
      float alpha = expf(m1 - nm);
      float p = expf(s1 - nm);
      float tsum = p;
#pragma unroll
      for (int o = 32; o >= 1; o >>= 1) tsum += __shfl_xor(tsum, o, 64);
      l1 = l1 * alpha + tsum;
      m1 = nm;
      ps[ub][lane] = p;
      o1 *= alpha;
    }
    if (hasA) {
#pragma unroll 16
      for (int j = 0; j < 64; ++j) o0 += ps[ua][j] * Vs[j][lane];
    }
    if (hasB) {
#pragma unroll 16
      for (int j = 0; j < 64; ++j) o1 += ps[ub][j] * Vs[j][lane];
    }
    __syncthreads();
  }
  int b = bh / H_, h = bh - b * H_;
  if (hasA) O[((size_t)b * L + lst[ua]) * DM + h * DH + lane] = o0 / l0;
  if (hasB) O[((size_t)b * L + lst[ub]) * DM + h * DH + lane] = o1 / l1;
}

// ---------------- x = LayerNorm(x) in place ----------------
__global__ void ln_kernel(float* __restrict__ X, const float* __restrict__ g,
                          const float* __restrict__ be) {
  __shared__ float red[256];
  int row = blockIdx.x, tid = threadIdx.x;
  size_t base = (size_t)row * DM;
  float t0 = X[base + tid];
  float t1 = X[base + tid + 256];
  red[tid] = t0 + t1;
  __syncthreads();
  for (int s = 128; s >= 1; s >>= 1) { if (tid < s) red[tid] += red[tid + s]; __syncthreads(); }
  float mu = red[0] / 512.0f;
  __syncthreads();
  float d0 = t0 - mu, d1 = t1 - mu;
  red[tid] = d0 * d0 + d1 * d1;
  __syncthreads();
  for (int s = 128; s >= 1; s >>= 1) { if (tid < s) red[tid] += red[tid + s]; __syncthreads(); }
  float rstd = 1.0f / sqrtf(red[0] / 512.0f + 1e-5f);
  X[base + tid] = d0 * rstd * g[tid] + be[tid];
  X[base + tid + 256] = d1 * rstd * g[tid + 256] + be[tid + 256];
}

// ---------------- maxpool k=3 s=2 pad=1 along L ----------------
__global__ void pool_kernel(const float* __restrict__ Y, float* __restrict__ X, int L2) {
  int i = blockIdx.x * 256 + threadIdx.x;
  int c = i % DM;
  int t = (i / DM) % L2;
  int b = i / (DM * L2);
  int L = L2 * 2;
  const float* yb = Y + (size_t)b * L * DM + c;
  float m = fmaxf(yb[(size_t)(2 * t) * DM], yb[(size_t)(2 * t + 1) * DM]);
  if (t > 0) m = fmaxf(m, yb[(size_t)(2 * t - 1) * DM]);
  X[i] = m;
}

// ---------------- column max, 2-stage ----------------
__global__ void colmax1_kernel(const float* __restrict__ X, float* __restrict__ P, int L) {
  int nlc = L >> 6;
  int bl = blockIdx.x;
  int b = bl / nlc, lc = bl % nlc;
  const float* xb = X + ((size_t)b * L + lc * 64) * DM;
  for (int c = threadIdx.x; c < DM; c += 256) {
    float m = -1e30f;
    for (int r = 0; r < 64; ++r) m = fmaxf(m, xb[(size_t)r * DM + c]);
    P[((size_t)b * nlc + lc) * DM + c] = m;
  }
}
__global__ void colmax2_kernel(const float* __restrict__ P, float* __restrict__ mc, int nlc) {
  int i = blockIdx.x * 256 + threadIdx.x;
  int b = i / DM, c = i % DM;
  float m = -1e30f;
  for (int lc = 0; lc < nlc; ++lc) m = fmaxf(m, P[((size_t)b * nlc + lc) * DM + c]);
  mc[i] = m;
}

// ---------------- final projection ----------------
__global__ void proj_kernel(const float* __restrict__ mc, const float* __restrict__ pw,
                            const float* __restrict__ pb, float* __restrict__ out) {
  __shared__ float red[256];
  int bo = blockIdx.x, b = bo / COUT, o = bo % COUT, tid = threadIdx.x;
  float s = mc[b * DM + tid] * pw[o * DM + tid] +
            mc[b * DM + tid + 256] * pw[o * DM + tid + 256];
  red[tid] = s;
  __syncthreads();
  for (int st = 128; st >= 1; st >>= 1) { if (tid < st) red[tid] += red[tid + st]; __syncthreads(); }
  if (tid == 0) out[bo] = red[0] + pb[o];
}

extern "C" void kernel_launch(void* const* d_in, const int* in_sizes, int n_in,
                              void* d_out, int out_size, void* d_ws, size_t ws_size,
                              hipStream_t stream) {
  (void)in_sizes; (void)n_in; (void)out_size;
  const float* xe   = (const float*)d_in[0];
  const float* tw   = (const float*)d_in[1];
  const float* Wq   = (const float*)d_in[2];
  const float* Wk   = (const float*)d_in[3];
  const float* Wv   = (const float*)d_in[4];
  const float* Wo   = (const float*)d_in[5];
  const float* bq   = (const float*)d_in[6];
  const float* bk   = (const float*)d_in[7];
  const float* bv   = (const float*)d_in[8];
  const float* bo   = (const float*)d_in[9];
  const float* W1   = (const float*)d_in[10];
  const float* b1   = (const float*)d_in[11];
  const float* W2   = (const float*)d_in[12];
  const float* b2   = (const float*)d_in[13];
  const float* ln1g = (const float*)d_in[14];
  const float* ln1b = (const float*)d_in[15];
  const float* ln2g = (const float*)d_in[16];
  const float* ln2b = (const float*)d_in[17];
  const float* dcw  = (const float*)d_in[18];
  const float* dcb  = (const float*)d_in[19];
  const float* bng  = (const float*)d_in[20];
  const float* bnb  = (const float*)d_in[21];
  const float* lnfg = (const float*)d_in[22];
  const float* lnfb = (const float*)d_in[23];
  const float* pw   = (const float*)d_in[24];
  const float* pb   = (const float*)d_in[25];
  float* out = (float*)d_out;

  float* Wf = (float*)d_ws;
  const size_t NB  = (size_t)B_ * LMAX * DM;
  const size_t NHB = (size_t)H_ * LMAX * DH;
  const size_t S_IDX = 81920, S_MV = 131072, S_TOP = 4096, S_VM = 4096,
               S_MC = 4096, S_P = 32768;
  const size_t PLANE = (size_t)512 * 1536;               // shorts per plane (max K)
  const size_t S_WP = 3 * PLANE / 2 + 1024;              // in floats
  const size_t SMALL = S_IDX + S_MV + S_TOP + S_VM + S_MC + S_P + S_WP + 1024;

  int g = 8;
  while (g > 1 && (2 * NB + 3 * (size_t)g * NHB + SMALL) * 4 > ws_size) g >>= 1;

  float* X  = Wf;
  float* T  = X + NB;
  float* Q  = T + NB;
  float* K  = Q + (size_t)g * NHB;
  float* V  = K + (size_t)g * NHB;
  float* SM = V + (size_t)g * NHB;
  int*   IDX = (int*)SM;
  float* Mv  = SM + S_IDX;
  int*   TOP = (int*)(Mv + S_MV);
  float* VM  = Mv + S_MV + S_TOP;
  float* MC  = VM + S_VM;
  float* P   = MC + S_MC;
  short* WP0 = (short*)(P + S_P);
  short* WP1 = WP0 + PLANE;
  short* WP2 = WP1 + PLANE;

  embed_kernel<<<B_ * LMAX * DM / 256, 256, 0, stream>>>(xe, tw, X);

  int L = LMAX;
  for (int i = 0; i < 3; ++i) {
    int U = (i == 0) ? 40 : 35;
    size_t wOff = (size_t)i * DM * DM;
    int ng = B_ / g;
    int nch = (U + 7) >> 3;
    const int NW = DM * DM;  // weight elems

    idx_kernel<<<(L * U + 255) / 256, 256, 0, stream>>>(IDX, L, U, i);

    for (int gb = 0; gb < ng; ++gb) {
      const float* Xg = X + (size_t)gb * g * L * DM;
      float* Tg = T + (size_t)gb * g * L * DM;
      dim3 gq(DM / 128, g * L / 128);
      wsplit_kernel<<<NW / 256, 256, 0, stream>>>(Wq + wOff, WP0, WP1, WP2, NW);
      mgemm<0, 1, 0, 0><<<gq, 256, 0, stream>>>(Xg, WP0, WP1, WP2, bq + i * DM, Q, L, DM);
      wsplit_kernel<<<NW / 256, 256, 0, stream>>>(Wk + wOff, WP0, WP1, WP2, NW);
      mgemm<0, 1, 0, 0><<<gq, 256, 0, stream>>>(Xg, WP0, WP1, WP2, bk + i * DM, K, L, DM);
      wsplit_kernel<<<NW / 256, 256, 0, stream>>>(Wv + wOff, WP0, WP1, WP2, NW);
      mgemm<0, 1, 0, 0><<<gq, 256, 0, stream>>>(Xg, WP0, WP1, WP2, bv + i * DM, V, L, DM);
      if (U == 40) qkM_t<40><<<g * H_ * L / 4, 256, 0, stream>>>(Q, K, IDX, Mv, L);
      else         qkM_t<35><<<g * H_ * L / 4, 256, 0, stream>>>(Q, K, IDX, Mv, L);
      topk_kernel<<<g * H_, 256, 0, stream>>>(Mv, TOP, L, U);
      vmean_kernel<<<g * H_, 256, 0, stream>>>(V, VM, L);
      fill_kernel<<<(unsigned)((size_t)g * L * DM / 256), 256, 0, stream>>>(VM, Tg, L);
      attn_fused<<<g * H_ * nch, 256, 0, stream>>>(Q, K, V, TOP, Tg, L, U);
    }

    dim3 gf(DM / 128, B_ * L / 128);
    wsplit_kernel<<<NW / 256, 256, 0, stream>>>(Wo + wOff, WP0, WP1, WP2, NW);
    mgemm<0, 0, 1, 0><<<gf, 256, 0, stream>>>(T, WP0, WP1, WP2, bo + i * DM, X, L, DM);
    ln_kernel<<<B_ * L, 256, 0, stream>>>(X, ln1g + i * DM, ln1b + i * DM);
    wsplit_kernel<<<NW / 256, 256, 0, stream>>>(W1 + wOff, WP0, WP1, WP2, NW);
    mgemm<1, 0, 0, 0><<<gf, 256, 0, stream>>>(X, WP0, WP1, WP2, b1 + i * DM, T, L, DM);
    wsplit_kernel<<<NW / 256, 256, 0, stream>>>(W2 + wOff, WP0, WP1, WP2, NW);
    mgemm<0, 0, 1, 0><<<gf, 256, 0, stream>>>(T, WP0, WP1, WP2, b2 + i * DM, X, L, DM);
    ln_kernel<<<B_ * L, 256, 0, stream>>>(X, ln2g + i * DM, ln2b + i * DM);

    if (i < 2) {
      wt3_kernel<<<DM * 1536 / 256, 256, 0, stream>>>(dcw + (size_t)i * DM * DM * 3,
                                                      WP0, WP1, WP2);
      mgemm<0, 0, 0, 1><<<gf, 256, 0, stream>>>(X, WP0, WP1, WP2, nullptr, T, L, 1536);
      bnelu_kernel<<<B_ * L * DM / 256, 256, 0, stream>>>(T, dcb + i * DM, bng + i * DM,
                                                          bnb + i * DM);
      L >>= 1;
      pool_kernel<<<B_ * L * DM / 256, 256, 0, stream>>>(T, X, L);
    }
  }

  ln_kernel<<<B_ * L, 256, 0, stream>>>(X, lnfg, lnfb);
  colmax1_kernel<<<B_ * (L >> 6), 256, 0, stream>>>(X, P, L);
  colmax2_kernel<<<B_ * DM / 256, 256, 0, stream>>>(P, MC, L >> 6);
  proj_kernel<<<B_ * COUT, 256, 0, stream>>>(MC, pw, pb, out);
}

// Round 17
// 2359.550 us; speedup vs baseline: 1.1406x; 1.1406x over previous
//
#include <hip/hip_runtime.h>

#define B_ 8
#define H_ 8
#define DM 512
#define DH 64
#define LMAX 2048
#define COUT 2

typedef __attribute__((ext_vector_type(8))) short frag8;
typedef __attribute__((ext_vector_type(4))) float f32x4;

typedef __attribute__((address_space(1))) const unsigned int guint;
typedef __attribute__((address_space(3))) unsigned int luint;
__device__ __forceinline__ void dma16(const short* g, short* l) {
  __builtin_amdgcn_global_load_lds((guint*)g, (luint*)l, 16, 0, 0);
}

__device__ __forceinline__ short f2bf(float v) {
  unsigned u = __float_as_uint(v);
  unsigned r = (u + 0x7fffu + ((u >> 16) & 1u)) >> 16;   // RNE
  return (short)r;
}
__device__ __forceinline__ float bf2f(short s) {
  return __uint_as_float(((unsigned)(unsigned short)s) << 16);
}

// ---------------- JAX threefry2x32 ----------------
__device__ __forceinline__ void tf2x32(unsigned k0, unsigned k1, unsigned x0, unsigned x1,
                                       unsigned& o0, unsigned& o1) {
  unsigned ks2 = k0 ^ k1 ^ 0x1BD11BDAu;
  x0 += k0; x1 += k1;
#define RND(r) { x0 += x1; x1 = (x1 << r) | (x1 >> (32 - r)); x1 ^= x0; }
  RND(13) RND(15) RND(26) RND(6)  x0 += k1;  x1 += ks2 + 1u;
  RND(17) RND(29) RND(16) RND(24) x0 += ks2; x1 += k0 + 2u;
  RND(13) RND(15) RND(26) RND(6)  x0 += k0;  x1 += k1 + 3u;
  RND(17) RND(29) RND(16) RND(24) x0 += k1;  x1 += ks2 + 4u;
  RND(13) RND(15) RND(26) RND(6)  x0 += ks2; x1 += k0 + 5u;
#undef RND
  o0 = x0; o1 = x1;
}

// VERIFIED (R7, absmax 0.0): Variant B partitionable. DO NOT TOUCH.
__global__ void idx_kernel(int* __restrict__ idxArr, int L, int U, int layer) {
  int p = blockIdx.x * 256 + threadIdx.x;
  int half = L * U;
  if (p >= half) return;
  unsigned fk0, fk1, k20, k21, o0, o1;
  tf2x32(0u, 42u, 0u, (unsigned)layer, fk0, fk1);
  tf2x32(fk0, fk1, 0u, 1u, k20, k21);
  tf2x32(k20, k21, 0u, (unsigned)p, o0, o1);
  idxArr[p] = (int)((o0 ^ o1) & (unsigned)(L - 1));
}

// ---------------- token embed + positional encoding ----------------
__global__ void embed_kernel(const float* __restrict__ xe, const float* __restrict__ tw,
                             float* __restrict__ X) {
  int i = blockIdx.x * 256 + threadIdx.x;
  int c = i % DM;
  int l = (i / DM) % LMAX;
  int b = i / (DM * LMAX);
  int lm = (l + LMAX - 1) & (LMAX - 1);
  int lp = (l + 1) & (LMAX - 1);
  const float* xb = xe + b * LMAX;
  float tok = tw[c * 3 + 0] * xb[lm] + tw[c * 3 + 1] * xb[l] + tw[c * 3 + 2] * xb[lp];
  float freq = expf(-(float)(c & ~1) * (9.210340371976184f / 512.0f));
  float ang = (float)l * freq;
  float pe = (c & 1) ? cosf(ang) : sinf(ang);
  X[i] = tok + pe;
}

// ---------------- split f32 -> 3 bf16 planes (weights AND activations) ----------------
__global__ void wsplit_kernel(const float* __restrict__ W, short* __restrict__ P0,
                              short* __restrict__ P1, short* __restrict__ P2, int n) {
  int i = blockIdx.x * 256 + threadIdx.x;
  if (i >= n) return;
  float v = W[i];
  short h0 = f2bf(v);
  float r1 = v - bf2f(h0);
  short h1 = f2bf(r1);
  float r2 = r1 - bf2f(h1);
  P0[i] = h0; P1[i] = h1; P2[i] = f2bf(r2);
}

// conv weight transpose + split: Pt[n][tap*512+k] = split(w[n][k][tap])
__global__ void wt3_kernel(const float* __restrict__ w, short* __restrict__ P0,
                           short* __restrict__ P1, short* __restrict__ P2) {
  int i = blockIdx.x * 256 + threadIdx.x;   // 512*1536
  int n = i / 1536, r = i - n * 1536, tap = r >> 9, k = r & 511;
  float v = w[((size_t)n * DM + k) * 3 + tap];
  short h0 = f2bf(v);
  float r1 = v - bf2f(h0);
  short h1 = f2bf(r1);
  float r2 = r1 - bf2f(h1);
  P0[i] = h0; P1[i] = h1; P2[i] = f2bf(r2);
}

// ---------------- bf16x3-split MFMA GEMM, DMA staging (m97-style) ----------------
// BM=BN=128, BK=32, 4 waves (2x2 of 64x64). A AND B staged from pre-split bf16
// planes via global_load_lds width=16 (48 x 1KB chunks/iter). 6 of 9 products.
// A planes: row stride DM (activations). B planes: row stride Ktot (weights).
template <int ACT, int QKV, int ACC, int CONV>
__global__ __launch_bounds__(256) void mgemm(const short* __restrict__ A0g,
                                             const short* __restrict__ A1g,
                                             const short* __restrict__ A2g,
                                             const short* __restrict__ W0g,
                                             const short* __restrict__ W1g,
                                             const short* __restrict__ W2g,
                                             const float* __restrict__ bias,
                                             float* __restrict__ C, int L, int Ktot) {
  __shared__ short A0[128 * 32], A1[128 * 32], A2[128 * 32];
  __shared__ short B0[128 * 32], B1[128 * 32], B2[128 * 32];
  int tid = threadIdx.x;
  int lane = tid & 63, wave = tid >> 6;
  int crow = lane >> 2, ckq = lane & 3;     // DMA: 16 rows x 4 k-groups per chunk
  // XCD-aware swizzle: each XCD gets one m-row phase, iterating n fastest.
  int gx = gridDim.x;
  int flat = blockIdx.y * gx + blockIdx.x;
  int mB, nB;
  if ((gridDim.y & 7) == 0) {
    int phase = flat & 7, sup = flat >> 3;
    nB = sup % gx;
    mB = phase + 8 * (sup / gx);
  } else {
    nB = blockIdx.x; mB = blockIdx.y;
  }
  int n0 = nB * 128, m0 = mB * 128;
  int wm = (wave >> 1) * 64, wn = (wave & 1) * 64;
  f32x4 acc[4][4] = {};
  int lrow = lane & 15, lq = lane >> 4;

  for (int k0 = 0; k0 < Ktot; k0 += 32) {
    int tap = 0, kcol = k0;
    if (CONV) { tap = k0 >> 9; kcol = k0 & 511; }
    // ---- A: 24 chunks (3 planes x 8), 6 per wave ----
#pragma unroll
    for (int q = 0; q < 6; ++q) {
      int gc = wave * 6 + q;               // 0..23
      int pl = gc >> 3, c = gc & 7;
      int grow = m0 + c * 16 + crow;
      const short* gp;
      if (CONV) {
        int b = grow / L, l = grow - b * L;
        int le = l + tap - 1;
        le = (le < 0) ? le + L : (le >= L ? le - L : le);
        gp = ((size_t)(b * L + le) * DM + kcol + ckq * 8) +
             (pl == 0 ? A0g : pl == 1 ? A1g : A2g);
      } else {
        gp = ((size_t)grow * DM + k0 + ckq * 8) +
             (pl == 0 ? A0g : pl == 1 ? A1g : A2g);
      }
      short* lp = (pl == 0 ? A0 : pl == 1 ? A1 : A2) + c * 512;
      dma16(gp, lp);
    }
    // ---- B: 24 chunks (3 planes x 8), 6 per wave ----
#pragma unroll
    for (int q = 0; q < 6; ++q) {
      int gc = wave * 6 + q;
      int pl = gc >> 3, c = gc & 7;
      int grow = n0 + c * 16 + crow;
      const short* gp = ((size_t)grow * Ktot + k0 + ckq * 8) +
                        (pl == 0 ? W0g : pl == 1 ? W1g : W2g);
      short* lp = (pl == 0 ? B0 : pl == 1 ? B1 : B2) + c * 512;
      dma16(gp, lp);
    }
    __syncthreads();
    frag8 a0f[4], a1f[4], a2f[4];
#pragma unroll
    for (int ti = 0; ti < 4; ++ti) {
      int off = (wm + ti * 16 + lrow) * 32 + lq * 8;
      a0f[ti] = *(const frag8*)&A0[off];
      a1f[ti] = *(const frag8*)&A1[off];
      a2f[ti] = *(const frag8*)&A2[off];
    }
#pragma unroll
    for (int tj = 0; tj < 4; ++tj) {
      int off = (wn + tj * 16 + lrow) * 32 + lq * 8;
      frag8 b0 = *(const frag8*)&B0[off];
      frag8 b1 = *(const frag8*)&B1[off];
      frag8 b2 = *(const frag8*)&B2[off];
#pragma unroll
      for (int ti = 0; ti < 4; ++ti) {
        f32x4 ac = acc[ti][tj];
        ac = __builtin_amdgcn_mfma_f32_16x16x32_bf16(a1f[ti], b1, ac, 0, 0, 0);
        ac = __builtin_amdgcn_mfma_f32_16x16x32_bf16(a0f[ti], b2, ac, 0, 0, 0);
        ac = __builtin_amdgcn_mfma_f32_16x16x32_bf16(a2f[ti], b0, ac, 0, 0, 0);
        ac = __builtin_amdgcn_mfma_f32_16x16x32_bf16(a0f[ti], b1, ac, 0, 0, 0);
        ac = __builtin_amdgcn_mfma_f32_16x16x32_bf16(a1f[ti], b0, ac, 0, 0, 0);
        ac = __builtin_amdgcn_mfma_f32_16x16x32_bf16(a0f[ti], b0, ac, 0, 0, 0);
        acc[ti][tj] = ac;
      }
    }
    __syncthreads();
  }
  // epilogue: C/D map col=lane&15, row=(lane>>4)*4+reg
#pragma unroll
  for (int ti = 0; ti < 4; ++ti) {
#pragma unroll
    for (int tj = 0; tj < 4; ++tj) {
#pragma unroll
      for (int r = 0; r < 4; ++r) {
        int row = m0 + wm + ti * 16 + lq * 4 + r;
        int col = n0 + wn + tj * 16 + lrow;
        float v = acc[ti][tj][r];
        if (!CONV) v += bias[col];
        if (ACT) v = 0.5f * v * (1.0f + erff(v * 0.70710678118654752f));
        if (QKV) {
          int b = row / L, l = row - b * L;
          int h = col >> 6, d = col & 63;
          C[(((size_t)b * H_ + h) * L + l) * DH + d] = v;
        } else if (ACC) {
          C[(size_t)row * DM + col] += v;
        } else {
          C[(size_t)row * DM + col] = v;
        }
      }
    }
  }
}

// ---------------- conv epilogue: BN + ELU ----------------
__global__ void bnelu_kernel(float* __restrict__ Y, const float* __restrict__ cb,
                             const float* __restrict__ g, const float* __restrict__ be) {
  int i = blockIdx.x * 256 + threadIdx.x;
  int c = i % DM;
  const float invs = 0.9999950000374997f;  // 1/sqrt(1+1e-5)
  float z = Y[i] + cb[c];
  z = z * invs * g[c] + be[c];
  Y[i] = z > 0.f ? z : expm1f(z);
}

// ---------------- qkM: lane=(dchunk,sample), 3 shuffles per 8-sample pass ----------------
template <int U>
__global__ void qkM_t(const float* __restrict__ Q, const float* __restrict__ Kd,
                      const int* __restrict__ idxArr, float* __restrict__ Mout, int L) {
  int lane = threadIdx.x & 63, wv = threadIdx.x >> 6;
  int row = blockIdx.x * 4 + wv;
  int l = row % L, bh = row / L;
  int u = lane & 7, dc = lane >> 3;       // sample slot, d-chunk
  const float* Qb = Q + ((size_t)bh * L + l) * DH + dc * 8;
  float4 q0 = *(const float4*)(Qb);
  float4 q1 = *(const float4*)(Qb + 4);
  const float* Kb = Kd + (size_t)bh * L * DH;
  const int* ip = idxArr + l * U;
  const int NP = (U + 7) / 8;
  float mx = -1e30f, sm = 0.f;
#pragma unroll
  for (int p = 0; p < NP; ++p) {
    int s = p * 8 + u;
    bool valid = (s < U);
    int ki = ip[valid ? s : 0];
    const float* kr = Kb + (size_t)ki * DH + dc * 8;
    float4 k0 = *(const float4*)(kr);
    float4 k1 = *(const float4*)(kr + 4);
    float d = q0.x * k0.x + q0.y * k0.y + q0.z * k0.z + q0.w * k0.w +
              q1.x * k1.x + q1.y * k1.y + q1.z * k1.z + q1.w * k1.w;
    d += __shfl_xor(d, 8, 64);
    d += __shfl_xor(d, 16, 64);
    d += __shfl_xor(d, 32, 64);
    if (valid) { mx = fmaxf(mx, d); sm += d; }
  }
#pragma unroll
  for (int o = 1; o <= 4; o <<= 1) {
    mx = fmaxf(mx, __shfl_xor(mx, o, 64));
    sm += __shfl_xor(sm, o, 64);
  }
  if (lane == 0) Mout[row] = mx - sm / (float)U;
}

// ---------------- top-U per bh ----------------
__global__ void topk_kernel(const float* __restrict__ M, int* __restrict__ top, int L, int U) {
  __shared__ float vals[LMAX];
  __shared__ float rv[256];
  __shared__ int ri[256];
  int bh = blockIdx.x, tid = threadIdx.x;
  for (int j = tid; j < L; j += 256) vals[j] = M[(size_t)bh * L + j];
  __syncthreads();
  for (int u = 0; u < U; ++u) {
    float bv = -1e30f; int bi = L;
    for (int j = tid; j < L; j += 256) {
      float v = vals[j];
      if (v > bv) { bv = v; bi = j; }
    }
    rv[tid] = bv; ri[tid] = bi;
    __syncthreads();
    for (int s = 128; s >= 1; s >>= 1) {
      if (tid < s) {
        float ov = rv[tid + s]; int oi = ri[tid + s];
        if (ov > rv[tid] || (ov == rv[tid] && oi < ri[tid])) { rv[tid] = ov; ri[tid] = oi; }
      }
      __syncthreads();
    }
    if (tid == 0) { top[bh * U + u] = ri[0]; vals[ri[0]] = -1e30f; }
    __syncthreads();
  }
}

// ---------------- v mean over L per (bh,d) ----------------
__global__ void vmean_kernel(const float* __restrict__ V, float* __restrict__ VM, int L) {
  __shared__ float red[256];
  int bh = blockIdx.x, tid = threadIdx.x, d = tid & 63, sq = tid >> 6;
  float s = 0.f;
  for (int l = sq; l < L; l += 4) s += V[((size_t)bh * L + l) * DH + d];
  red[tid] = s;
  __syncthreads();
  if (sq == 0) VM[bh * DH + d] = (red[d] + red[d + 64] + red[d + 128] + red[d + 192]) / (float)L;
}

// ---------------- fill ctx (g,L,DM) with v-mean ----------------
__global__ void fill_kernel(const float* __restrict__ VM, float* __restrict__ O, int L) {
  size_t i = (size_t)blockIdx.x * 256 + threadIdx.x;
  int c = (int)(i % DM);
  int b = (int)(i / ((size_t)L * DM));
  O[i] = VM[b * DM + c];
}

// ---------------- flash-style attention for selected queries ----------------
__global__ __launch_bounds__(256) void attn_fused(const float* __restrict__ Q,
                                                  const float* __restrict__ Kd,
                                                  const float* __restrict__ V,
                                                  const int* __restrict__ top,
                                                  float* __restrict__ O, int L, int U) {
  __shared__ float Qs[8][64];
  __shared__ float Kt[64][65];
  __shared__ float Vs[64][68];
  __shared__ float ps[8][64];
  __shared__ int lst[8];
  int nch = (U + 7) >> 3;
  int bh = blockIdx.x / nch, ch = blockIdx.x - bh * nch;
  int u0g = ch * 8;
  int qn = U - u0g; if (qn > 8) qn = 8;
  int tid = threadIdx.x, lane = tid & 63, wv = tid >> 6;
  if (tid < qn) lst[tid] = top[bh * U + u0g + tid];
  __syncthreads();
  for (int idx = tid; idx < qn * 64; idx += 256) {
    int u = idx >> 6, d = idx & 63;
    Qs[u][d] = Q[((size_t)bh * L + lst[u]) * DH + d];
  }
  __syncthreads();
  int ua = wv, ub = wv + 4;
  bool hasA = ua < qn, hasB = ub < qn;
  float m0 = -1e30f, l0 = 0.f, o0 = 0.f;
  float m1 = -1e30f, l1 = 0.f, o1 = 0.f;
  const float* Kbase = Kd + (size_t)bh * L * DH;
  const float* Vbase = V + (size_t)bh * L * DH;
  for (int t0 = 0; t0 < L; t0 += 64) {
#pragma unroll
    for (int it = 0; it < 4; ++it) {
      int idx = tid + it * 256;
      int j = idx >> 4, d4 = (idx & 15) * 4;
      float4 kv = *(const float4*)(Kbase + (size_t)(t0 + j) * DH + d4);
      Kt[d4 + 0][j] = kv.x; Kt[d4 + 1][j] = kv.y;
      Kt[d4 + 2][j] = kv.z; Kt[d4 + 3][j] = kv.w;
      *(float4*)&Vs[j][d4] = *(const float4*)(Vbase + (size_t)(t0 + j) * DH + d4);
    }
    __syncthreads();
    float s0 = 0.f, s1 = 0.f;
#pragma unroll 16
    for (int d = 0; d < 64; ++d) {
      float kd = Kt[d][lane];
      s0 += kd * Qs[ua & 7][d];
      s1 += kd * Qs[ub & 7][d];
    }
    s0 *= 0.125f; s1 *= 0.125f;
    if (hasA) {
      float tm = s0;
#pragma unroll
      for (int o = 32; o >= 1; o >>= 1) tm = fmaxf(tm, __shfl_xor(tm, o, 64));
      float nm = fmaxf(m0, tm);
      float alpha = expf(m0 - nm);
      float p = expf(s0 - nm);
      float tsum = p;
#pragma unroll
      for (int o = 32; o >= 1; o >>= 1) tsum += __shfl_xor(tsum, o, 64);
      l0 = l0 * alpha + tsum;
      m0 = nm;
      ps[ua][lane] = p;
      o0 *= alpha;
    }
    if (hasB) {
      float tm = s1;
#pragma unroll
      for (int o = 32; o >= 1; o >>= 1) tm = fmaxf(tm, __shfl_xor(tm, o, 64));
      float nm = fmaxf(m1, tm);
      float alpha = expf(m1 - nm);
      float p = expf(s1 - nm);
      float tsum = p;
#pragma unroll
      for (int o = 32; o >= 1; o >>= 1) tsum += __shfl_xor(tsum, o, 64);
      l1 = l1 * alpha + tsum;
      m1 = nm;
      ps[ub][lane] = p;
      o1 *= alpha;
    }
    if (hasA) {
#pragma unroll 16
      for (int j = 0; j < 64; ++j) o0 += ps[ua][j] * Vs[j][lane];
    }
    if (hasB) {
#pragma unroll 16
      for (int j = 0; j < 64; ++j) o1 += ps[ub][j] * Vs[j][lane];
    }
    __syncthreads();
  }
  int b = bh / H_, h = bh - b * H_;
  if (hasA) O[((size_t)b * L + lst[ua]) * DM + h * DH + lane] = o0 / l0;
  if (hasB) O[((size_t)b * L + lst[ub]) * DM + h * DH + lane] = o1 / l1;
}

// ---------------- x = LayerNorm(x) in place ----------------
__global__ void ln_kernel(float* __restrict__ X, const float* __restrict__ g,
                          const float* __restrict__ be) {
  __shared__ float red[256];
  int row = blockIdx.x, tid = threadIdx.x;
  size_t base = (size_t)row * DM;
  float t0 = X[base + tid];
  float t1 = X[base + tid + 256];
  red[tid] = t0 + t1;
  __syncthreads();
  for (int s = 128; s >= 1; s >>= 1) { if (tid < s) red[tid] += red[tid + s]; __syncthreads(); }
  float mu = red[0] / 512.0f;
  __syncthreads();
  float d0 = t0 - mu, d1 = t1 - mu;
  red[tid] = d0 * d0 + d1 * d1;
  __syncthreads();
  for (int s = 128; s >= 1; s >>= 1) { if (tid < s) red[tid] += red[tid + s]; __syncthreads(); }
  float rstd = 1.0f / sqrtf(red[0] / 512.0f + 1e-5f);
  X[base + tid] = d0 * rstd * g[tid] + be[tid];
  X[base + tid + 256] = d1 * rstd * g[tid + 256] + be[tid + 256];
}

// ---------------- maxpool k=3 s=2 pad=1 along L ----------------
__global__ void pool_kernel(const float* __restrict__ Y, float* __restrict__ X, int L2) {
  int i = blockIdx.x * 256 + threadIdx.x;
  int c = i % DM;
  int t = (i / DM) % L2;
  int b = i / (DM * L2);
  int L = L2 * 2;
  const float* yb = Y + (size_t)b * L * DM + c;
  float m = fmaxf(yb[(size_t)(2 * t) * DM], yb[(size_t)(2 * t + 1) * DM]);
  if (t > 0) m = fmaxf(m, yb[(size_t)(2 * t - 1) * DM]);
  X[i] = m;
}

// ---------------- column max, 2-stage ----------------
__global__ void colmax1_kernel(const float* __restrict__ X, float* __restrict__ P, int L) {
  int nlc = L >> 6;
  int bl = blockIdx.x;
  int b = bl / nlc, lc = bl % nlc;
  const float* xb = X + ((size_t)b * L + lc * 64) * DM;
  for (int c = threadIdx.x; c < DM; c += 256) {
    float m = -1e30f;
    for (int r = 0; r < 64; ++r) m = fmaxf(m, xb[(size_t)r * DM + c]);
    P[((size_t)b * nlc + lc) * DM + c] = m;
  }
}
__global__ void colmax2_kernel(const float* __restrict__ P, float* __restrict__ mc, int nlc) {
  int i = blockIdx.x * 256 + threadIdx.x;
  int b = i / DM, c = i % DM;
  float m = -1e30f;
  for (int lc = 0; lc < nlc; ++lc) m = fmaxf(m, P[((size_t)b * nlc + lc) * DM + c]);
  mc[i] = m;
}

// ---------------- final projection ----------------
__global__ void proj_kernel(const float* __restrict__ mc, const float* __restrict__ pw,
                            const float* __restrict__ pb, float* __restrict__ out) {
  __shared__ float red[256];
  int bo = blockIdx.x, b = bo / COUT, o = bo % COUT, tid = threadIdx.x;
  float s = mc[b * DM + tid] * pw[o * DM + tid] +
            mc[b * DM + tid + 256] * pw[o * DM + tid + 256];
  red[tid] = s;
  __syncthreads();
  for (int st = 128; st >= 1; st >>= 1) { if (tid < st) red[tid] += red[tid + st]; __syncthreads(); }
  if (tid == 0) out[bo] = red[0] + pb[o];
}

extern "C" void kernel_launch(void* const* d_in, const int* in_sizes, int n_in,
                              void* d_out, int out_size, void* d_ws, size_t ws_size,
                              hipStream_t stream) {
  (void)in_sizes; (void)n_in; (void)out_size;
  const float* xe   = (const float*)d_in[0];
  const float* tw   = (const float*)d_in[1];
  const float* Wq   = (const float*)d_in[2];
  const float* Wk   = (const float*)d_in[3];
  const float* Wv   = (const float*)d_in[4];
  const float* Wo   = (const float*)d_in[5];
  const float* bq   = (const float*)d_in[6];
  const float* bk   = (const float*)d_in[7];
  const float* bv   = (const float*)d_in[8];
  const float* bo   = (const float*)d_in[9];
  const float* W1   = (const float*)d_in[10];
  const float* b1   = (const float*)d_in[11];
  const float* W2   = (const float*)d_in[12];
  const float* b2   = (const float*)d_in[13];
  const float* ln1g = (const float*)d_in[14];
  const float* ln1b = (const float*)d_in[15];
  const float* ln2g = (const float*)d_in[16];
  const float* ln2b = (const float*)d_in[17];
  const float* dcw  = (const float*)d_in[18];
  const float* dcb  = (const float*)d_in[19];
  const float* bng  = (const float*)d_in[20];
  const float* bnb  = (const float*)d_in[21];
  const float* lnfg = (const float*)d_in[22];
  const float* lnfb = (const float*)d_in[23];
  const float* pw   = (const float*)d_in[24];
  const float* pb   = (const float*)d_in[25];
  float* out = (float*)d_out;

  float* Wf = (float*)d_ws;
  const size_t NB  = (size_t)B_ * LMAX * DM;             // 8,388,608 floats
  const size_t NHB = (size_t)H_ * LMAX * DH;             // 1,048,576 floats
  const size_t S_IDX = 81920, S_MV = 131072, S_TOP = 4096, S_VM = 4096,
               S_MC = 4096, S_P = 32768;
  const size_t PLANE  = (size_t)512 * 1536;              // weight plane (shorts)
  const size_t APLANE = NB;                              // activation plane (shorts)
  const size_t S_WP = 3 * PLANE / 2 + 1024;              // floats
  const size_t S_AP = 3 * APLANE / 2 + 1024;             // floats
  const size_t SMALL = S_IDX + S_MV + S_TOP + S_VM + S_MC + S_P + S_WP + S_AP + 1024;

  int g = 8;
  while (g > 1 && (2 * NB + 3 * (size_t)g * NHB + SMALL) * 4 > ws_size) g >>= 1;

  float* X  = Wf;
  float* T  = X + NB;
  float* Q  = T + NB;
  float* K  = Q + (size_t)g * NHB;
  float* V  = K + (size_t)g * NHB;
  float* SM = V + (size_t)g * NHB;
  int*   IDX = (int*)SM;
  float* Mv  = SM + S_IDX;
  int*   TOP = (int*)(Mv + S_MV);
  float* VM  = Mv + S_MV + S_TOP;
  float* MC  = VM + S_VM;
  float* P   = MC + S_MC;
  short* WP0 = (short*)(P + S_P);
  short* WP1 = WP0 + PLANE;
  short* WP2 = WP1 + PLANE;
  short* AP0 = (short*)((float*)(P + S_P) + S_WP);
  short* AP1 = AP0 + APLANE;
  short* AP2 = AP1 + APLANE;

  embed_kernel<<<B_ * LMAX * DM / 256, 256, 0, stream>>>(xe, tw, X);

  int L = LMAX;
  for (int i = 0; i < 3; ++i) {
    int U = (i == 0) ? 40 : 35;
    size_t wOff = (size_t)i * DM * DM;
    int ng = B_ / g;
    int nch = (U + 7) >> 3;
    const int NW = DM * DM;

    idx_kernel<<<(L * U + 255) / 256, 256, 0, stream>>>(IDX, L, U, i);

    for (int gb = 0; gb < ng; ++gb) {
      const float* Xg = X + (size_t)gb * g * L * DM;
      float* Tg = T + (size_t)gb * g * L * DM;
      int Mg = g * L * DM;
      dim3 gq(DM / 128, g * L / 128);
      wsplit_kernel<<<Mg / 256, 256, 0, stream>>>(Xg, AP0, AP1, AP2, Mg);
      wsplit_kernel<<<NW / 256, 256, 0, stream>>>(Wq + wOff, WP0, WP1, WP2, NW);
      mgemm<0, 1, 0, 0><<<gq, 256, 0, stream>>>(AP0, AP1, AP2, WP0, WP1, WP2,
                                                bq + i * DM, Q, L, DM);
      wsplit_kernel<<<NW / 256, 256, 0, stream>>>(Wk + wOff, WP0, WP1, WP2, NW);
      mgemm<0, 1, 0, 0><<<gq, 256, 0, stream>>>(AP0, AP1, AP2, WP0, WP1, WP2,
                                                bk + i * DM, K, L, DM);
      wsplit_kernel<<<NW / 256, 256, 0, stream>>>(Wv + wOff, WP0, WP1, WP2, NW);
      mgemm<0, 1, 0, 0><<<gq, 256, 0, stream>>>(AP0, AP1, AP2, WP0, WP1, WP2,
                                                bv + i * DM, V, L, DM);
      if (U == 40) qkM_t<40><<<g * H_ * L / 4, 256, 0, stream>>>(Q, K, IDX, Mv, L);
      else         qkM_t<35><<<g * H_ * L / 4, 256, 0, stream>>>(Q, K, IDX, Mv, L);
      topk_kernel<<<g * H_, 256, 0, stream>>>(Mv, TOP, L, U);
      vmean_kernel<<<g * H_, 256, 0, stream>>>(V, VM, L);
      fill_kernel<<<(unsigned)((size_t)g * L * DM / 256), 256, 0, stream>>>(VM, Tg, L);
      attn_fused<<<g * H_ * nch, 256, 0, stream>>>(Q, K, V, TOP, Tg, L, U);
    }

    int Mf = B_ * L * DM;
    dim3 gf(DM / 128, B_ * L / 128);
    wsplit_kernel<<<Mf / 256, 256, 0, stream>>>(T, AP0, AP1, AP2, Mf);
    wsplit_kernel<<<NW / 256, 256, 0, stream>>>(Wo + wOff, WP0, WP1, WP2, NW);
    mgemm<0, 0, 1, 0><<<gf, 256, 0, stream>>>(AP0, AP1, AP2, WP0, WP1, WP2,
                                              bo + i * DM, X, L, DM);
    ln_kernel<<<B_ * L, 256, 0, stream>>>(X, ln1g + i * DM, ln1b + i * DM);
    wsplit_kernel<<<Mf / 256, 256, 0, stream>>>(X, AP0, AP1, AP2, Mf);
    wsplit_kernel<<<NW / 256, 256, 0, stream>>>(W1 + wOff, WP0, WP1, WP2, NW);
    mgemm<1, 0, 0, 0><<<gf, 256, 0, stream>>>(AP0, AP1, AP2, WP0, WP1, WP2,
                                              b1 + i * DM, T, L, DM);
    wsplit_kernel<<<Mf / 256, 256, 0, stream>>>(T, AP0, AP1, AP2, Mf);
    wsplit_kernel<<<NW / 256, 256, 0, stream>>>(W2 + wOff, WP0, WP1, WP2, NW);
    mgemm<0, 0, 1, 0><<<gf, 256, 0, stream>>>(AP0, AP1, AP2, WP0, WP1, WP2,
                                              b2 + i * DM, X, L, DM);
    ln_kernel<<<B_ * L, 256, 0, stream>>>(X, ln2g + i * DM, ln2b + i * DM);

    if (i < 2) {
      wsplit_kernel<<<Mf / 256, 256, 0, stream>>>(X, AP0, AP1, AP2, Mf);
      wt3_kernel<<<DM * 1536 / 256, 256, 0, stream>>>(dcw + (size_t)i * DM * DM * 3,
                                                      WP0, WP1, WP2);
      mgemm<0, 0, 0, 1><<<gf, 256, 0, stream>>>(AP0, AP1, AP2, WP0, WP1, WP2,
                                                nullptr, T, L, 1536);
      bnelu_kernel<<<B_ * L * DM / 256, 256, 0, stream>>>(T, dcb + i * DM, bng + i * DM,
                                                          bnb + i * DM);
      L >>= 1;
      pool_kernel<<<B_ * L * DM / 256, 256, 0, stream>>>(T, X, L);
    }
  }

  ln_kernel<<<B_ * L, 256, 0, stream>>>(X, lnfg, lnfb);
  colmax1_kernel<<<B_ * (L >> 6), 256, 0, stream>>>(X, P, L);
  colmax2_kernel<<<B_ * DM / 256, 256, 0, stream>>>(P, MC, L >> 6);
  proj_kernel<<<B_ * COUT, 256, 0, stream>>>(MC, pw, pb, out);
}